// Round 1
// baseline (9.658 us; speedup 1.0000x reference)
//
#include <hip/hip_runtime.h>
#include <math.h>

#define NUM_ANCHORS 3
#define ATTRIB 85
#define RATIO_THRESH 4.0f

__global__ void yolo_iou_kernel(const float* __restrict__ pred0,
                                const float* __restrict__ pred1,
                                const float* __restrict__ pred2,
                                const float* __restrict__ targets,
                                const float* __restrict__ anchors0,
                                const float* __restrict__ anchors1,
                                const float* __restrict__ anchors2,
                                float* __restrict__ out,
                                int T) {
    int idx = blockIdx.x * blockDim.x + threadIdx.x;
    int total = 3 * NUM_ANCHORS * T;
    if (idx >= total) return;

    int layer = idx / (NUM_ANCHORS * T);
    int rem   = idx - layer * NUM_ANCHORS * T;
    int a     = rem / T;
    int t     = rem - a * T;

    const float* pred;
    const float* anchors;
    int g;
    if (layer == 0)      { pred = pred0; anchors = anchors0; g = 19; }
    else if (layer == 1) { pred = pred1; anchors = anchors1; g = 38; }
    else                 { pred = pred2; anchors = anchors2; g = 76; }

    // targets row: [bidx, cls, x, y, w, h]
    const float* tr = targets + (size_t)t * 6;
    float bidx_f = tr[0];
    float x = tr[2];
    float y = tr[3];
    float w = tr[4];
    float h = tr[5];

    float gf = (float)g;
    float gx  = x * gf;   // gxy
    float gy  = y * gf;
    float gww = w * gf;   // gwh
    float ghh = h * gf;

    float aw = anchors[a * 2 + 0];
    float ah = anchors[a * 2 + 1];

    // keep mask: max(r, 1/r) over both dims < thresh
    float rw = gww / aw;
    float rh = ghh / ah;
    float rmax = fmaxf(fmaxf(rw, 1.0f / rw), fmaxf(rh, 1.0f / rh));
    bool keep = rmax < RATIO_THRESH;

    // int truncation matches jnp astype(int32)
    int b  = (int)bidx_f;
    int gi = (int)gx;
    int gj = (int)gy;
    gi = min(max(gi, 0), g - 1);
    gj = min(max(gj, 0), g - 1);

    // tbox = [gxy - clipped_gij, gwh]
    float tbx = gx - (float)gi;
    float tby = gy - (float)gj;
    float tbw = gww;
    float tbh = ghh;

    // gather ps = pred[b, a, gj, gi, 0:4]; layout (B, 3, g, g, 85)
    size_t base = ((((size_t)b * NUM_ANCHORS + a) * g + gj) * g + gi) * (size_t)ATTRIB;
    float p0 = pred[base + 0];
    float p1 = pred[base + 1];
    float p2 = pred[base + 2];
    float p3 = pred[base + 3];

    float px = 1.0f / (1.0f + expf(-p0));
    float py = 1.0f / (1.0f + expf(-p1));
    float pw = expf(p2) * aw;
    float ph = expf(p3) * ah;

    // IoU (xywh)
    float b1x1 = px - pw * 0.5f, b1x2 = px + pw * 0.5f;
    float b1y1 = py - ph * 0.5f, b1y2 = py + ph * 0.5f;
    float b2x1 = tbx - tbw * 0.5f, b2x2 = tbx + tbw * 0.5f;
    float b2y1 = tby - tbh * 0.5f, b2y2 = tby + tbh * 0.5f;

    float iw = fminf(b1x2, b2x2) - fmaxf(b1x1, b2x1);
    float ih = fminf(b1y2, b2y2) - fmaxf(b1y1, b2y1);
    iw = fmaxf(iw, 0.0f);
    ih = fmaxf(ih, 0.0f);
    float inter = iw * ih;
    float uni = pw * ph + tbw * tbh - inter + 1e-9f;
    float iou = inter / uni;

    out[idx] = keep ? iou : 0.0f;
}

extern "C" void kernel_launch(void* const* d_in, const int* in_sizes, int n_in,
                              void* d_out, int out_size, void* d_ws, size_t ws_size,
                              hipStream_t stream) {
    const float* pred0    = (const float*)d_in[0];
    const float* pred1    = (const float*)d_in[1];
    const float* pred2    = (const float*)d_in[2];
    const float* targets  = (const float*)d_in[3];
    const float* anchors0 = (const float*)d_in[4];
    const float* anchors1 = (const float*)d_in[5];
    const float* anchors2 = (const float*)d_in[6];
    float* out = (float*)d_out;

    int T = in_sizes[3] / 6;           // targets is (T, 6)
    int total = 3 * NUM_ANCHORS * T;   // 1800 for T=200
    int block = 256;
    int grid = (total + block - 1) / block;

    yolo_iou_kernel<<<grid, block, 0, stream>>>(pred0, pred1, pred2, targets,
                                                anchors0, anchors1, anchors2,
                                                out, T);
}